// Round 22
// baseline (305.364 us; speedup 1.0000x reference)
//
#include <hip/hip_runtime.h>
#include <hip/hip_fp16.h>
#include <cstdint>
#include <cstddef>

#define N_NODES 100000
#define E_EDGES 6400000
#define E_TOT   (E_EDGES + N_NODES)
#define IN_CH   128
#define NHID    16              // HEADS*HID
#define BSHIFT  8               // 256 dsts per bucket
#define BSZ     256
#define NBUCK   391             // ceil(100000/256)
#define CHUNK   8192            // edges per bin block
#define NCHUNK  ((E_TOT + CHUNK - 1) / CHUNK)   // 794
#define SLAB    17664           // staged slots per bucket (mean 16640, sd 129: +7.9 sigma)
#define LCAP    17664           // LDS csr capacity == SLAB
#define BCAP2   28              // LDS staging per bucket (lambda 20.9; ~50 direct/block)

// ---------------- detection: int64 vs int32 edge_index ----------------
__global__ void k_detect(const int* __restrict__ edge, int* __restrict__ flag) {
    if (blockIdx.x == 0 && threadIdx.x == 0) {
        int odd_or = 0;
        for (int i = 0; i < 64; i++) odd_or |= edge[2 * i + 1];
        flag[0] = (odd_or == 0) ? 1 : 0;   // 1 => data is int64 little-endian
    }
}

// ------- layer-1 node features: h16 rows + split alpha arrays ---------
__global__ __launch_bounds__(256) void k_gemm1(
        const float* __restrict__ x, const float* __restrict__ W1,
        const float* __restrict__ a_src1, const float* __restrict__ a_dst1,
        __half* __restrict__ h16, float* __restrict__ asrc,
        float* __restrict__ adst) {
    __shared__ __align__(16) float sW[IN_CH * NHID];   // 8 KB
    __shared__ __align__(16) float sx[16][132];        // padded stride
    __shared__ float sh[16][17];
    int t = threadIdx.x;
    int r = t >> 4, c = t & 15;
    int row = blockIdx.x * 16 + r;

    const float4* W4 = (const float4*)W1;
    ((float4*)sW)[t] = W4[t];
    ((float4*)sW)[t + 256] = W4[t + 256];

    if (row < N_NODES) {
        const float4* xr = (const float4*)(x + (size_t)row * IN_CH);
        float4 v0 = xr[c];
        float4 v1 = xr[c + 16];
        *(float4*)&sx[r][4 * c] = v0;
        *(float4*)&sx[r][64 + 4 * c] = v1;
    }
    __syncthreads();

    float acc = 0.f;
    if (row < N_NODES) {
        #pragma unroll 16
        for (int k = 0; k < IN_CH; k++) acc = fmaf(sx[r][k], sW[k * NHID + c], acc);
        h16[(size_t)row * NHID + c] = __float2half(acc);
    }
    sh[r][c] = acc;
    __syncthreads();

    if (row < N_NODES && c < 4) {
        int h = c & 1;
        const float* av = (c >= 2) ? a_dst1 : a_src1;
        float s = 0.f;
        #pragma unroll
        for (int q = 0; q < 8; q++) s = fmaf(sh[r][h * 8 + q], av[h * 8 + q], s);
        if (c < 2) asrc[2 * (size_t)row + c] = s;
        else       adst[2 * (size_t)row + (c - 2)] = s;
    }
}

// ------- slab cursor init (re-run every launch: deterministic) --------
__global__ void k_binit(int* __restrict__ bcur) {
    int i = blockIdx.x * 256 + threadIdx.x;
    if (i < NBUCK) bcur[i * 16] = i * SLAB;
}

// --- single-pass binning into per-bucket slabs. LDS staging + bulk
// reservation (proven R19/R20 flush structure: lbase in LDS, barrier,
// 16-group coalesced flush). Overflow edges take their own slot via a
// direct atomicAdd at put-time (~50/block) — no replay machinery.
__global__ __launch_bounds__(256) void k_bin2(const int* __restrict__ edge,
                                              const int* __restrict__ flag,
                                              int* __restrict__ bcur,
                                              unsigned* __restrict__ staged) {
    __shared__ unsigned lbin[NBUCK][BCAP2];   // 43.8 KB
    __shared__ int lcnt[NBUCK];
    __shared__ int lbase[NBUCK];
    int m64 = flag[0];
    int t = threadIdx.x;
    int g = t >> 4, lane = t & 15;

    size_t c0 = (size_t)blockIdx.x * CHUNK;
    if (c0 >= E_TOT) return;
    size_t cend = c0 + CHUNK; if (cend > E_TOT) cend = E_TOT;
    size_t ee = (cend < (size_t)E_EDGES) ? cend : (size_t)E_EDGES;

    for (int i = t; i < NBUCK; i += 256) lcnt[i] = 0;
    __syncthreads();

    auto put = [&](int s, int d) {
        int b = d >> BSHIFT;
        unsigned v = (unsigned)s | ((unsigned)(d & (BSZ - 1)) << 17);
        int idx = atomicAdd(&lcnt[b], 1);
        if (idx < BCAP2) lbin[b][idx] = v;
        else {
            int slot = atomicAdd(&bcur[b * 16], 1);  // rare exact path
            staged[slot] = v;
        }
    };

    if (m64) {
        const int4* sp = (const int4*)edge;
        const int4* dp = (const int4*)(edge + 2 * (size_t)E_EDGES);
        for (size_t i = c0 + 2 * t; i < ee; i += 512) {
            int4 sv = sp[i >> 1];
            int4 dv = dp[i >> 1];
            put(sv.x, dv.x);
            if (i + 1 < ee) put(sv.z, dv.z);
        }
    } else {
        const int4* sp = (const int4*)edge;
        const int4* dp = (const int4*)(edge + (size_t)E_EDGES);
        for (size_t i = c0 + 4 * t; i < ee; i += 1024) {
            int4 sv = sp[i >> 2];
            int4 dv = dp[i >> 2];
            put(sv.x, dv.x);
            if (i + 1 < ee) put(sv.y, dv.y);
            if (i + 2 < ee) put(sv.z, dv.z);
            if (i + 3 < ee) put(sv.w, dv.w);
        }
    }
    size_t sl0 = (c0 > (size_t)E_EDGES) ? c0 : (size_t)E_EDGES;
    for (size_t i = sl0 + t; i < cend; i += 256) {
        int d = (int)(i - E_EDGES);
        put(d, d);
    }
    __syncthreads();

    // bulk reservation: one thread per bucket, result in LDS
    for (int b = t; b < NBUCK; b += 256) {
        int n = lcnt[b]; if (n > BCAP2) n = BCAP2;
        if (n) lbase[b] = atomicAdd(&bcur[b * 16], n);
    }
    __syncthreads();

    // cooperative coalesced flush (proven structure)
    for (int b = g; b < NBUCK; b += 16) {
        int n = lcnt[b]; if (n > BCAP2) n = BCAP2;
        if (!n) continue;
        int pos = lbase[b];
        for (int i = lane; i < n; i += 16) staged[pos + i] = lbin[b][i];
    }
}

// --- fused layer-1: compact-LDS counting sort + pair-lane aggregation -
// One block per 256-dst bucket, reading its slab [bkt*SLAB, bcur).
// LDS csr as u16 + bit-17 bitset (~43KB). Writes offs (seg begin) and
// eoffs (seg end) so k_edge2 tolerates slab gaps.
__global__ __launch_bounds__(512) void k_fused1(
        const unsigned* __restrict__ staged, const int* __restrict__ bcur,
        const __half* __restrict__ h16, const float* __restrict__ asrc,
        const float* __restrict__ adst,
        const float* __restrict__ b1, const float* __restrict__ W2,
        int* __restrict__ csr, int* __restrict__ offs, int* __restrict__ eoffs,
        float* __restrict__ h2out) {
    __shared__ unsigned short lcsr16[LCAP];   // 34.5 KB
    __shared__ unsigned hib[LCAP / 32];       // 2.2 KB
    __shared__ int hist[BSZ];
    __shared__ int segbeg[BSZ];
    __shared__ int cur[BSZ];
    __shared__ float2 sadp[BSZ];              // 2 KB
    int bkt = blockIdx.x;
    int t = threadIdx.x;
    int dbase = bkt << BSHIFT;
    int beg = bkt * SLAB;
    int end = bcur[bkt * 16];                 // slab start + count

    if (t < BSZ) {
        hist[t] = 0;
        int d = dbase + t;
        sadp[t] = (d < N_NODES) ? ((const float2*)adst)[d] : make_float2(0.f, 0.f);
    }
    for (int i = t; i < LCAP / 32; i += 512) hib[i] = 0;
    __syncthreads();
    for (int e = beg + t; e < end; e += 512)
        atomicAdd(&hist[staged[e] >> 17], 1);
    __syncthreads();

    // scan hist (first 256 threads), publish segbeg/cur/offs
    int myv = (t < BSZ) ? hist[t] : 0;
    __syncthreads();
    for (int ofs = 1; ofs < BSZ; ofs <<= 1) {
        int a = 0, b = 0;
        if (t < BSZ) { a = hist[t]; b = (t >= ofs) ? hist[t - ofs] : 0; }
        __syncthreads();
        if (t < BSZ) hist[t] = a + b;
        __syncthreads();
    }
    if (t < BSZ) {
        int excl = hist[t] - myv;
        segbeg[t] = excl;
        cur[t] = excl;
        int d = dbase + t;
        if (d < N_NODES) offs[d] = beg + excl;
    }
    __syncthreads();

    for (int e = beg + t; e < end; e += 512) {
        unsigned v = staged[e];
        int s = (int)(v & 0x1FFFFu);
        int pos = atomicAdd(&cur[v >> 17], 1);
        lcsr16[pos] = (unsigned short)s;
        if (s >> 16) atomicOr(&hib[pos >> 5], 1u << (pos & 31));
    }
    __syncthreads();

    // per-dst end offsets for k_edge2 (cur[] now holds segment ends)
    if (t < BSZ) {
        int d = dbase + t;
        if (d < N_NODES) eoffs[d] = beg + cur[t];
    }

    auto getsrc = [&](int i) {
        return (int)lcsr16[i] | (int)(((hib[i >> 5] >> (i & 31)) & 1u) << 16);
    };

    // dump sorted list for k_edge2 (coalesced, slab layout)
    int n = end - beg;
    for (int i = t; i < n; i += 512) csr[beg + i] = getsrc(i);

    // ---- aggregation: pair (t>>1) owns dst, sub = head ----
    int p = t >> 1, sub = t & 1;
    int sb = segbeg[p], se = cur[p];
    float adpv = sub ? sadp[p].y : sadp[p].x;

    float acc[8];
    #pragma unroll
    for (int c = 0; c < 8; c++) acc[c] = 0.f;
    float den = 0.f;

    auto loadslot = [&](int i, float& aspv, float4& hv) {
        if (i < se) {
            int s = getsrc(i);
            hv = *(const float4*)(h16 + (size_t)s * NHID + sub * 8);  // 32B row: 1 line
            aspv = asrc[2 * (size_t)s + sub];    // pair adjacent 4B: merged txn
        }
    };
    auto consume = [&](float aspv, const float4& hv) {
        float a = aspv + adpv; a = (a > 0.f) ? a : 0.2f * a;
        float pw = __expf(a);
        den += pw;
        const __half2* hh = (const __half2*)&hv;
        #pragma unroll
        for (int q = 0; q < 4; q++) {
            float2 f = __half22float2(hh[q]);
            acc[2 * q]     = fmaf(pw, f.x, acc[2 * q]);
            acc[2 * q + 1] = fmaf(pw, f.y, acc[2 * q + 1]);
        }
    };

    float aA = 0.f, aB = 0.f, aC = 0.f, aD = 0.f, aE = 0.f, aF = 0.f;
    float4 z4 = make_float4(0.f, 0.f, 0.f, 0.f);
    float4 hA = z4, hB = z4, hC = z4, hD = z4, hE = z4, hF = z4;

    int i = sb;
    loadslot(i,     aA, hA);
    loadslot(i + 1, aB, hB);
    loadslot(i + 2, aC, hC);
    loadslot(i + 3, aD, hD);
    loadslot(i + 4, aE, hE);
    loadslot(i + 5, aF, hF);
    while (true) {
        if (i >= se) break;
        consume(aA, hA); loadslot(i + 6, aA, hA); i++;
        if (i >= se) break;
        consume(aB, hB); loadslot(i + 6, aB, hB); i++;
        if (i >= se) break;
        consume(aC, hC); loadslot(i + 6, aC, hC); i++;
        if (i >= se) break;
        consume(aD, hD); loadslot(i + 6, aD, hD); i++;
        if (i >= se) break;
        consume(aE, hE); loadslot(i + 6, aE, hE); i++;
        if (i >= se) break;
        consume(aF, hF); loadslot(i + 6, aF, hF); i++;
    }

    float inv = 1.f / (den + 1e-16f);
    float v = 0.f;
    #pragma unroll
    for (int ch = 0; ch < 8; ch++) {
        float o = acc[ch] * inv + b1[8 * sub + ch];
        o = (o > 0.f) ? o : 0.f;
        v = fmaf(o, W2[8 * sub + ch], v);
    }
    v += __shfl_xor(v, 1, 64);      // add partner head's contribution
    if (sub == 0) {
        int d = dbase + p;
        if (d < N_NODES) h2out[d] = v;
    }
}

// ------------- layer-2 edge pass (CSR walk, 6-deep pipeline) ----------
__global__ __launch_bounds__(256) void k_edge2(
        const int* __restrict__ offs, const int* __restrict__ eoffs,
        const int* __restrict__ csr, const float* __restrict__ h2,
        const float* __restrict__ a_src2, const float* __restrict__ a_dst2,
        const float* __restrict__ b2, float* __restrict__ out) {
    int t = threadIdx.x;
    int g = t >> 4, lane = t & 15;
    int d = blockIdx.x * 16 + g;
    if (d >= N_NODES) return;

    float as2 = a_src2[0], ad2 = a_dst2[0];
    float adv = h2[d] * ad2;
    int beg = offs[d], end = eoffs[d];

    float den = 0.f, acc = 0.f;
    auto ls = [&](int ee, float& hs) { if (ee < end) hs = h2[csr[ee]]; };
    auto cs = [&](float hs) {
        float a = fmaf(hs, as2, adv);
        a = (a > 0.f) ? a : 0.2f * a;
        float p = __expf(a);
        den += p;
        acc = fmaf(p, hs, acc);
    };
    float hA = 0.f, hB = 0.f, hC = 0.f, hD = 0.f, hE = 0.f, hF = 0.f;
    int e = beg + lane;
    ls(e, hA); ls(e + 16, hB); ls(e + 32, hC);
    ls(e + 48, hD); ls(e + 64, hE); ls(e + 80, hF);
    while (true) {
        if (e >= end) break;
        cs(hA); ls(e + 96, hA); e += 16;
        if (e >= end) break;
        cs(hB); ls(e + 96, hB); e += 16;
        if (e >= end) break;
        cs(hC); ls(e + 96, hC); e += 16;
        if (e >= end) break;
        cs(hD); ls(e + 96, hD); e += 16;
        if (e >= end) break;
        cs(hE); ls(e + 96, hE); e += 16;
        if (e >= end) break;
        cs(hF); ls(e + 96, hF); e += 16;
    }
    #pragma unroll
    for (int m = 1; m < 16; m <<= 1) {
        den += __shfl_xor(den, m, 64);
        acc += __shfl_xor(acc, m, 64);
    }
    if (lane == 0) out[d] = acc / (den + 1e-16f) + b2[0];
}

// ---------------- launch ----------------
extern "C" void kernel_launch(void* const* d_in, const int* in_sizes, int n_in,
                              void* d_out, int out_size, void* d_ws, size_t ws_size,
                              hipStream_t stream) {
    const float* x      = (const float*)d_in[0];
    const int*   edge   = (const int*)  d_in[1];
    const float* W1     = (const float*)d_in[2];
    const float* a_src1 = (const float*)d_in[3];
    const float* a_dst1 = (const float*)d_in[4];
    const float* b1     = (const float*)d_in[5];
    const float* W2     = (const float*)d_in[6];
    const float* a_src2 = (const float*)d_in[7];
    const float* a_dst2 = (const float*)d_in[8];
    const float* b2     = (const float*)d_in[9];

    constexpr size_t A = 256;
    auto al = [](size_t b) { return (b + A - 1) / A * A; };
    char* ws = (char*)d_ws;
    size_t off = 0;
    int*      flag   = (int*)(ws + off);      off += al(256);
    int*      bcur   = (int*)(ws + off);      off += al((size_t)NBUCK * 16 * 4);     // 25 KB padded
    unsigned* staged = (unsigned*)(ws + off); off += al((size_t)NBUCK * SLAB * 4);   // 27.6 MB
    int*      csr    = (int*)(ws + off);      off += al((size_t)NBUCK * SLAB * 4);   // 27.6 MB
    int*      offs   = (int*)(ws + off);      off += al((size_t)N_NODES * 4);
    int*      eoffs  = (int*)(ws + off);      off += al((size_t)N_NODES * 4);
    __half*   h16    = (__half*)(ws + off);   off += al((size_t)N_NODES * NHID * 2); // 3.2 MB
    float*    asrc   = (float*)(ws + off);    off += al((size_t)N_NODES * 2 * 4);    // 0.8 MB
    float*    adst   = (float*)(ws + off);    off += al((size_t)N_NODES * 2 * 4);    // 0.8 MB
    float*    h2     = (float*)(ws + off);    off += al((size_t)N_NODES * 4);
    (void)ws_size; (void)in_sizes; (void)n_in; (void)out_size;

    k_detect<<<1, 64, 0, stream>>>(edge, flag);
    k_gemm1 <<<(N_NODES + 15) / 16, 256, 0, stream>>>(x, W1, a_src1, a_dst1, h16, asrc, adst);
    k_binit <<<2, 256, 0, stream>>>(bcur);
    k_bin2  <<<NCHUNK, 256, 0, stream>>>(edge, flag, bcur, staged);
    k_fused1<<<NBUCK, 512, 0, stream>>>(staged, bcur, h16, asrc, adst, b1, W2,
                                        csr, offs, eoffs, h2);
    k_edge2 <<<(N_NODES + 15) / 16, 256, 0, stream>>>(offs, eoffs, csr, h2,
                                                      a_src2, a_dst2, b2, (float*)d_out);
}

// Round 23
// 196.508 us; speedup vs baseline: 1.5540x; 1.5540x over previous
//
#include <hip/hip_runtime.h>
#include <hip/hip_fp16.h>
#include <cstdint>
#include <cstddef>

#define N_NODES 100000
#define E_EDGES 6400000
#define E_TOT   (E_EDGES + N_NODES)
#define IN_CH   128
#define NHID    16              // HEADS*HID
#define RECB    64              // bytes per node record: h16[16] + asrc0/1 + pad
#define BSHIFT  8               // 256 dsts per bucket
#define BSZ     256
#define NBUCK   391             // ceil(100000/256)
#define CHUNK   8192            // edges per bin/count block
#define BCAP    24              // LDS staging per bucket (lambda 20.9; exact slow path)
#define NCHUNK  ((E_TOT + CHUNK - 1) / CHUNK)   // 794
#define LCAP    18176           // LDS csr capacity (mean 16640, sd 129: +12 sigma)

// ---------------- detection: int64 vs int32 edge_index ----------------
__global__ void k_detect(const int* __restrict__ edge, int* __restrict__ flag) {
    if (blockIdx.x == 0 && threadIdx.x == 0) {
        int odd_or = 0;
        for (int i = 0; i < 64; i++) odd_or |= edge[2 * i + 1];
        flag[0] = (odd_or == 0) ? 1 : 0;   // 1 => data is int64 little-endian
    }
}

// ------- layer-1 node features: 64B record {h16 row, asrc pair} -------
__global__ __launch_bounds__(256) void k_gemm1(
        const float* __restrict__ x, const float* __restrict__ W1,
        const float* __restrict__ a_src1, const float* __restrict__ a_dst1,
        char* __restrict__ rec, float* __restrict__ adst) {
    __shared__ __align__(16) float sW[IN_CH * NHID];   // 8 KB
    __shared__ __align__(16) float sx[16][132];        // padded stride
    __shared__ float sh[16][17];
    int t = threadIdx.x;
    int r = t >> 4, c = t & 15;
    int row = blockIdx.x * 16 + r;

    const float4* W4 = (const float4*)W1;
    ((float4*)sW)[t] = W4[t];
    ((float4*)sW)[t + 256] = W4[t + 256];

    if (row < N_NODES) {
        const float4* xr = (const float4*)(x + (size_t)row * IN_CH);
        float4 v0 = xr[c];
        float4 v1 = xr[c + 16];
        *(float4*)&sx[r][4 * c] = v0;
        *(float4*)&sx[r][64 + 4 * c] = v1;
    }
    __syncthreads();

    float acc = 0.f;
    if (row < N_NODES) {
        #pragma unroll 16
        for (int k = 0; k < IN_CH; k++) acc = fmaf(sx[r][k], sW[k * NHID + c], acc);
        ((__half*)(rec + (size_t)row * RECB))[c] = __float2half(acc);
    }
    sh[r][c] = acc;
    __syncthreads();

    if (row < N_NODES && c < 4) {
        int h = c & 1;
        const float* av = (c >= 2) ? a_dst1 : a_src1;
        float s = 0.f;
        #pragma unroll
        for (int q = 0; q < 8; q++) s = fmaf(sh[r][h * 8 + q], av[h * 8 + q], s);
        if (c < 2) ((float*)(rec + (size_t)row * RECB + 32))[c] = s;
        else       adst[2 * (size_t)row + (c - 2)] = s;
    }
}

// --- per-chunk 391-bucket histogram; int4-vectorized edge reads -------
__global__ __launch_bounds__(256) void k_ccount(const int* __restrict__ edge,
                                                const int* __restrict__ flag,
                                                int* __restrict__ ccnt) {
    __shared__ int sc[NBUCK];
    int m64 = flag[0];
    int t = threadIdx.x;
    for (int i = t; i < NBUCK; i += 256) sc[i] = 0;
    __syncthreads();
    size_t c0 = (size_t)blockIdx.x * CHUNK;
    size_t cend = c0 + CHUNK; if (cend > E_TOT) cend = E_TOT;
    size_t ee = (cend < (size_t)E_EDGES) ? cend : (size_t)E_EDGES;

    if (m64) {
        const int4* dp = (const int4*)(edge + 2 * (size_t)E_EDGES);
        for (size_t i = c0 + 2 * t; i < ee; i += 512) {
            int4 v = dp[i >> 1];                 // dsts of edges i, i+1
            atomicAdd(&sc[v.x >> BSHIFT], 1);
            if (i + 1 < ee) atomicAdd(&sc[v.z >> BSHIFT], 1);
        }
    } else {
        const int4* dp = (const int4*)(edge + (size_t)E_EDGES);
        for (size_t i = c0 + 4 * t; i < ee; i += 1024) {
            int4 v = dp[i >> 2];                 // dsts of edges i..i+3
            atomicAdd(&sc[v.x >> BSHIFT], 1);
            if (i + 1 < ee) atomicAdd(&sc[v.y >> BSHIFT], 1);
            if (i + 2 < ee) atomicAdd(&sc[v.z >> BSHIFT], 1);
            if (i + 3 < ee) atomicAdd(&sc[v.w >> BSHIFT], 1);
        }
    }
    size_t sl0 = (c0 > (size_t)E_EDGES) ? c0 : (size_t)E_EDGES;
    for (size_t i = sl0 + t; i < cend; i += 256) {
        int d = (int)(i - E_EDGES);              // self-loop: no memory read
        atomicAdd(&sc[d >> BSHIFT], 1);
    }
    __syncthreads();
    for (int i = t; i < NBUCK; i += 256)
        ccnt[(size_t)blockIdx.x * NBUCK + i] = sc[i];
}

// --- per-bucket exclusive scan over chunks: exact per-chunk bases -----
__global__ __launch_bounds__(256) void k_cscan(int* __restrict__ ccnt,
                                               int* __restrict__ bcnt) {
    __shared__ int sd[256];
    __shared__ int carry;
    int b = blockIdx.x, t = threadIdx.x;
    if (t == 0) carry = 0;
    __syncthreads();
    for (int base = 0; base < NCHUNK; base += 256) {
        int c = base + t;
        int v = (c < NCHUNK) ? ccnt[(size_t)c * NBUCK + b] : 0;
        sd[t] = v;
        __syncthreads();
        for (int ofs = 1; ofs < 256; ofs <<= 1) {
            int a = sd[t];
            int bb = (t >= ofs) ? sd[t - ofs] : 0;
            __syncthreads();
            sd[t] = a + bb;
            __syncthreads();
        }
        if (c < NCHUNK) ccnt[(size_t)c * NBUCK + b] = sd[t] - v + carry;
        __syncthreads();
        if (t == 255) carry += sd[255];
        __syncthreads();
    }
    if (t == 0) bcnt[b] = carry;
}

// ---------------- scan over 391 bucket totals ----------------
__global__ __launch_bounds__(512) void k_bscan(const int* __restrict__ bcnt,
                                               int* __restrict__ bbase) {
    __shared__ int sd[512];
    int t = threadIdx.x;
    int v = (t < NBUCK) ? bcnt[t] : 0;
    sd[t] = v;
    __syncthreads();
    for (int ofs = 1; ofs < 512; ofs <<= 1) {
        int a = sd[t];
        int b = (t >= ofs) ? sd[t - ofs] : 0;
        __syncthreads();
        sd[t] = a + b;
        __syncthreads();
    }
    if (t < NBUCK) bbase[t] = sd[t] - v;        // exclusive
    if (t == NBUCK) bbase[NBUCK] = sd[NBUCK - 1];
}

// ------ binning with precomputed exact slots: ZERO global atomics -----
__global__ __launch_bounds__(256) void k_bin(const int* __restrict__ edge,
                                             const int* __restrict__ flag,
                                             const int* __restrict__ ccnt,
                                             const int* __restrict__ bbase,
                                             unsigned* __restrict__ staged) {
    __shared__ unsigned lbin[NBUCK][BCAP];   // 36.7 KB -> 4 blocks/CU
    __shared__ int lcnt[NBUCK];
    __shared__ int lbase[NBUCK];
    int m64 = flag[0];
    int t = threadIdx.x;
    int g = t >> 4, lane = t & 15;

    size_t c0 = (size_t)blockIdx.x * CHUNK;
    if (c0 >= E_TOT) return;
    size_t cend = c0 + CHUNK; if (cend > E_TOT) cend = E_TOT;
    size_t ee = (cend < (size_t)E_EDGES) ? cend : (size_t)E_EDGES;

    for (int i = t; i < NBUCK; i += 256) {
        lcnt[i] = 0;
        lbase[i] = bbase[i] + ccnt[(size_t)blockIdx.x * NBUCK + i];
    }
    __syncthreads();

    auto put = [&](int s, int d) {
        int b = d >> BSHIFT;
        unsigned v = (unsigned)s | ((unsigned)(d & (BSZ - 1)) << 17);
        int idx = atomicAdd(&lcnt[b], 1);
        if (idx < BCAP) lbin[b][idx] = v;
        else            staged[lbase[b] + idx] = v;   // exact slot, no atomic
    };

    if (m64) {
        const int4* sp = (const int4*)edge;
        const int4* dp = (const int4*)(edge + 2 * (size_t)E_EDGES);
        for (size_t i = c0 + 2 * t; i < ee; i += 512) {
            int4 sv = sp[i >> 1];
            int4 dv = dp[i >> 1];
            put(sv.x, dv.x);
            if (i + 1 < ee) put(sv.z, dv.z);
        }
    } else {
        const int4* sp = (const int4*)edge;
        const int4* dp = (const int4*)(edge + (size_t)E_EDGES);
        for (size_t i = c0 + 4 * t; i < ee; i += 1024) {
            int4 sv = sp[i >> 2];
            int4 dv = dp[i >> 2];
            put(sv.x, dv.x);
            if (i + 1 < ee) put(sv.y, dv.y);
            if (i + 2 < ee) put(sv.z, dv.z);
            if (i + 3 < ee) put(sv.w, dv.w);
        }
    }
    size_t sl0 = (c0 > (size_t)E_EDGES) ? c0 : (size_t)E_EDGES;
    for (size_t i = sl0 + t; i < cend; i += 256) {
        int d = (int)(i - E_EDGES);
        put(d, d);
    }
    __syncthreads();
    // cooperative coalesced flush of the LDS-staged majority
    for (int b = g; b < NBUCK; b += 16) {
        int n = min(lcnt[b], BCAP);
        if (!n) continue;
        int pos = lbase[b];
        for (int i = lane; i < n; i += 16) staged[pos + i] = lbin[b][i];
    }
}

// --- fused layer-1: LDS counting sort + pair-lane aggregation ---------
// One block per 256-dst bucket. Phase 1: hist+scan+scatter the bucket's
// ~16.6k edges into LDS csr, then coalesced dump to global for k_edge2.
// Phase 2: one lane-pair per dst walks its LDS segment; per edge one
// 64B record line (h16+asrc); per-lane register acc (own head);
// finalize fuses softmax-div + bias + ReLU + @W2.
__global__ __launch_bounds__(512) void k_fused1(
        const unsigned* __restrict__ staged, const int* __restrict__ bbase,
        const char* __restrict__ rec, const float* __restrict__ adst,
        const float* __restrict__ b1, const float* __restrict__ W2,
        int* __restrict__ csr, int* __restrict__ offs,
        float* __restrict__ h2out) {
    __shared__ int lcsr[LCAP];        // 71 KB
    __shared__ int hist[BSZ];
    __shared__ int segbeg[BSZ];
    __shared__ int cur[BSZ];
    __shared__ float2 sadp[BSZ];      // 2 KB
    int bkt = blockIdx.x;
    int t = threadIdx.x;
    int dbase = bkt << BSHIFT;
    int beg = bbase[bkt], end = bbase[bkt + 1];

    if (t < BSZ) {
        hist[t] = 0;
        int d = dbase + t;
        sadp[t] = (d < N_NODES) ? ((const float2*)adst)[d] : make_float2(0.f, 0.f);
    }
    __syncthreads();
    for (int e = beg + t; e < end; e += 512)
        atomicAdd(&hist[staged[e] >> 17], 1);
    __syncthreads();

    // scan hist (first 256 threads), publish segbeg/cur/offs
    int myv = (t < BSZ) ? hist[t] : 0;
    __syncthreads();
    for (int ofs = 1; ofs < BSZ; ofs <<= 1) {
        int a = 0, b = 0;
        if (t < BSZ) { a = hist[t]; b = (t >= ofs) ? hist[t - ofs] : 0; }
        __syncthreads();
        if (t < BSZ) hist[t] = a + b;
        __syncthreads();
    }
    if (t < BSZ) {
        int excl = hist[t] - myv;
        segbeg[t] = excl;
        cur[t] = excl;
        int d = dbase + t;
        if (d < N_NODES) offs[d] = beg + excl;
    }
    if (bkt == NBUCK - 1 && t == 0) offs[N_NODES] = E_TOT;
    __syncthreads();

    for (int e = beg + t; e < end; e += 512) {
        unsigned v = staged[e];
        int pos = atomicAdd(&cur[v >> 17], 1);
        lcsr[pos] = (int)(v & 0x1FFFFu);
    }
    __syncthreads();

    // dump sorted list for k_edge2 (coalesced)
    int n = end - beg;
    for (int i = t; i < n; i += 512) csr[beg + i] = lcsr[i];

    // ---- aggregation: pair (t>>1) owns dst, sub = head ----
    int p = t >> 1, sub = t & 1;
    int sb = segbeg[p], se = cur[p];       // cur == segment end after scatter
    float adpv = sub ? sadp[p].y : sadp[p].x;

    float acc[8];
    #pragma unroll
    for (int c = 0; c < 8; c++) acc[c] = 0.f;
    float den = 0.f;

    auto loadslot = [&](int i, float& aspv, float4& hv) {
        if (i < se) {
            int s = lcsr[i];
            const char* rp = rec + (size_t)s * RECB;
            hv = *(const float4*)(rp + sub * 16);
            aspv = *(const float*)(rp + 32 + 4 * sub);   // same 64B line
        }
    };
    auto consume = [&](float aspv, const float4& hv) {
        float a = aspv + adpv; a = (a > 0.f) ? a : 0.2f * a;
        float pw = __expf(a);
        den += pw;
        const __half2* hh = (const __half2*)&hv;
        #pragma unroll
        for (int q = 0; q < 4; q++) {
            float2 f = __half22float2(hh[q]);
            acc[2 * q]     = fmaf(pw, f.x, acc[2 * q]);
            acc[2 * q + 1] = fmaf(pw, f.y, acc[2 * q + 1]);
        }
    };

    float aA = 0.f, aB = 0.f, aC = 0.f, aD = 0.f;
    float4 z4 = make_float4(0.f, 0.f, 0.f, 0.f);
    float4 hA = z4, hB = z4, hC = z4, hD = z4;

    int i = sb;
    loadslot(i,     aA, hA);
    loadslot(i + 1, aB, hB);
    loadslot(i + 2, aC, hC);
    loadslot(i + 3, aD, hD);
    while (true) {
        if (i >= se) break;
        consume(aA, hA); loadslot(i + 4, aA, hA); i++;
        if (i >= se) break;
        consume(aB, hB); loadslot(i + 4, aB, hB); i++;
        if (i >= se) break;
        consume(aC, hC); loadslot(i + 4, aC, hC); i++;
        if (i >= se) break;
        consume(aD, hD); loadslot(i + 4, aD, hD); i++;
    }

    float inv = 1.f / (den + 1e-16f);
    float v = 0.f;
    #pragma unroll
    for (int ch = 0; ch < 8; ch++) {
        float o = acc[ch] * inv + b1[8 * sub + ch];
        o = (o > 0.f) ? o : 0.f;
        v = fmaf(o, W2[8 * sub + ch], v);
    }
    v += __shfl_xor(v, 1, 64);      // add partner head's contribution
    if (sub == 0) {
        int d = dbase + p;
        if (d < N_NODES) h2out[d] = v;
    }
}

// ------------- layer-2 edge pass (CSR walk, 6-deep pipeline) ----------
__global__ __launch_bounds__(256) void k_edge2(
        const int* __restrict__ offs, const int* __restrict__ csr,
        const float* __restrict__ h2,
        const float* __restrict__ a_src2, const float* __restrict__ a_dst2,
        const float* __restrict__ b2, float* __restrict__ out) {
    int t = threadIdx.x;
    int g = t >> 4, lane = t & 15;
    int d = blockIdx.x * 16 + g;
    if (d >= N_NODES) return;

    float as2 = a_src2[0], ad2 = a_dst2[0];
    float adv = h2[d] * ad2;
    int beg = offs[d], end = offs[d + 1];

    float den = 0.f, acc = 0.f;
    auto ls = [&](int ee, float& hs) { if (ee < end) hs = h2[csr[ee]]; };
    auto cs = [&](float hs) {
        float a = fmaf(hs, as2, adv);
        a = (a > 0.f) ? a : 0.2f * a;
        float p = __expf(a);
        den += p;
        acc = fmaf(p, hs, acc);
    };
    float hA = 0.f, hB = 0.f, hC = 0.f, hD = 0.f, hE = 0.f, hF = 0.f;
    int e = beg + lane;
    ls(e, hA); ls(e + 16, hB); ls(e + 32, hC);
    ls(e + 48, hD); ls(e + 64, hE); ls(e + 80, hF);
    while (true) {
        if (e >= end) break;
        cs(hA); ls(e + 96, hA); e += 16;
        if (e >= end) break;
        cs(hB); ls(e + 96, hB); e += 16;
        if (e >= end) break;
        cs(hC); ls(e + 96, hC); e += 16;
        if (e >= end) break;
        cs(hD); ls(e + 96, hD); e += 16;
        if (e >= end) break;
        cs(hE); ls(e + 96, hE); e += 16;
        if (e >= end) break;
        cs(hF); ls(e + 96, hF); e += 16;
    }
    #pragma unroll
    for (int m = 1; m < 16; m <<= 1) {
        den += __shfl_xor(den, m, 64);
        acc += __shfl_xor(acc, m, 64);
    }
    if (lane == 0) out[d] = acc / (den + 1e-16f) + b2[0];
}

// ---------------- launch ----------------
extern "C" void kernel_launch(void* const* d_in, const int* in_sizes, int n_in,
                              void* d_out, int out_size, void* d_ws, size_t ws_size,
                              hipStream_t stream) {
    const float* x      = (const float*)d_in[0];
    const int*   edge   = (const int*)  d_in[1];
    const float* W1     = (const float*)d_in[2];
    const float* a_src1 = (const float*)d_in[3];
    const float* a_dst1 = (const float*)d_in[4];
    const float* b1     = (const float*)d_in[5];
    const float* W2     = (const float*)d_in[6];
    const float* a_src2 = (const float*)d_in[7];
    const float* a_dst2 = (const float*)d_in[8];
    const float* b2     = (const float*)d_in[9];

    constexpr size_t A = 256;
    auto al = [](size_t b) { return (b + A - 1) / A * A; };
    char* ws = (char*)d_ws;
    size_t off = 0;
    int*      flag   = (int*)(ws + off);      off += al(256);
    int*      ccnt   = (int*)(ws + off);      off += al((size_t)NCHUNK * NBUCK * 4); // 1.24 MB
    int*      bcnt   = (int*)(ws + off);      off += al(NBUCK * 4);
    int*      bbase  = (int*)(ws + off);      off += al((NBUCK + 1) * 4);
    unsigned* staged = (unsigned*)(ws + off); off += al((size_t)E_TOT * 4);          // 26 MB
    int*      csr    = (int*)(ws + off);      off += al((size_t)E_TOT * 4);          // 26 MB
    int*      offs   = (int*)(ws + off);      off += al((size_t)(N_NODES + 1) * 4);
    char*     rec    = (char*)(ws + off);     off += al((size_t)N_NODES * RECB);     // 6.4 MB
    float*    adst   = (float*)(ws + off);    off += al((size_t)N_NODES * 2 * 4);    // 0.8 MB
    float*    h2     = (float*)(ws + off);    off += al((size_t)N_NODES * 4);
    (void)ws_size; (void)in_sizes; (void)n_in; (void)out_size;

    k_detect<<<1, 64, 0, stream>>>(edge, flag);
    k_gemm1 <<<(N_NODES + 15) / 16, 256, 0, stream>>>(x, W1, a_src1, a_dst1, rec, adst);
    k_ccount<<<NCHUNK, 256, 0, stream>>>(edge, flag, ccnt);
    k_cscan <<<NBUCK, 256, 0, stream>>>(ccnt, bcnt);
    k_bscan <<<1, 512, 0, stream>>>(bcnt, bbase);
    k_bin   <<<NCHUNK, 256, 0, stream>>>(edge, flag, ccnt, bbase, staged);
    k_fused1<<<NBUCK, 512, 0, stream>>>(staged, bbase, rec, adst, b1, W2, csr, offs, h2);
    k_edge2 <<<(N_NODES + 15) / 16, 256, 0, stream>>>(offs, csr, h2, a_src2, a_dst2, b2,
                                                      (float*)d_out);
}